// Round 2
// baseline (214.154 us; speedup 1.0000x reference)
//
#include <hip/hip_runtime.h>

// Problem constants (fixed by setup_inputs)
#define U   128
#define T_  256
#define N_  1024
#define TN  (T_ * N_)             // 262144 elements in final output

// ws layout (floats): [0] = sum(final), [1] = sum(input_spikes), [2..129] = w[j]

// Single block, 1024 threads: column sums of gated conn with 16-deep ILP.
__global__ __launch_bounds__(1024) void prep_kernel(const float* __restrict__ conn,
                                                    float* __restrict__ ws) {
    __shared__ float part[8][U];
    int tid = threadIdx.x;
    int c = tid >> 7;          // 0..7  (i-chunk)
    int j = tid & 127;         // 0..127 (column)
    float s = 0.0f;
#pragma unroll
    for (int k = 0; k < 16; ++k) {
        float v = conn[(c * 16 + k) * U + j];    // lanes: consecutive j -> coalesced
        s += (v > 0.1f) ? v : 0.0f;
    }
    part[c][j] = s;
    __syncthreads();
    if (tid < 2) ws[tid] = 0.0f;                 // zero accumulators (ws poisoned 0xAA)
    if (tid < U) {
        float t = 0.0f;
#pragma unroll
        for (int cc = 0; cc < 8; ++cc) t += part[cc][tid];
        ws[2 + tid] = 3.0f * t;
    }
}

// Scalar main: 1024 blocks x 256 threads = one thread per output float.
// 4 blocks/CU -> 16 waves/CU; unroll 16 -> 16 outstanding dword loads/lane.
__global__ __launch_bounds__(256) void main_kernel(const float* __restrict__ uo,   // [U][TN]
                                                   const float* __restrict__ tgt,  // [TN]
                                                   const float* __restrict__ insp, // [TN]
                                                   float* __restrict__ out,        // [TN]
                                                   float* __restrict__ ws) {
    __shared__ float w_s[U];
    int tid = threadIdx.x;
    if (tid < U) w_s[tid] = ws[2 + tid];
    __syncthreads();

    int idx = blockIdx.x * 256 + tid;            // 0..TN-1
    const float* p = uo + idx;

    float acc = 0.0f;
#pragma unroll 16
    for (int j = 0; j < U; ++j)
        acc += w_s[j] * __builtin_nontemporal_load(p + (size_t)j * TN);

    float r = acc * 0.5f + 1.5f * tgt[idx];
    out[idx] = r;
    float lin = insp[idx];

    // Block-level reductions: sum(final), sum(input_spikes)
#pragma unroll
    for (int off = 32; off > 0; off >>= 1) {
        r   += __shfl_down(r,   off, 64);
        lin += __shfl_down(lin, off, 64);
    }
    __shared__ float red[8];
    int wave = tid >> 6;
    int lane = tid & 63;
    if (lane == 0) { red[wave] = r; red[4 + wave] = lin; }
    __syncthreads();
    if (tid == 0) {
        atomicAdd(&ws[0], red[0] + red[1] + red[2] + red[3]);
        atomicAdd(&ws[1], red[4] + red[5] + red[6] + red[7]);
    }
}

// Conditional boost: with this data mean >> 0.2, so the branch is dead and
// this kernel only reads ws[0..1]; the generic path is kept for correctness.
__global__ __launch_bounds__(256) void boost_kernel(const float4* __restrict__ rb,
                                                    float4* __restrict__ out,
                                                    const float* __restrict__ ws) {
    float mean    = ws[0] * (1.0f / TN);
    float in_rate = ws[1] * (1000.0f / TN);      // input_spikes.mean() * 1000
    float target_mean = (in_rate + 20.0f) * 0.01f;
    float boost = fmaxf(0.0f, target_mean - mean);
    if (mean < 0.2f) {
        int idx = blockIdx.x * 256 + threadIdx.x;
        float4 o = out[idx];
        float4 r = rb[idx];
        float b2 = boost * 2.0f;
        o.x += r.x * b2;
        o.y += r.y * b2;
        o.z += r.z * b2;
        o.w += r.w * b2;
        out[idx] = o;
    }
}

extern "C" void kernel_launch(void* const* d_in, const int* in_sizes, int n_in,
                              void* d_out, int out_size, void* d_ws, size_t ws_size,
                              hipStream_t stream) {
    const float* input_spikes = (const float*)d_in[0];   // [T,N]
    const float* unit_outputs = (const float*)d_in[1];   // [U,T,N]
    const float* conn         = (const float*)d_in[2];   // [U,U]
    const float* target       = (const float*)d_in[3];   // [T,N]
    const float* rand_bias    = (const float*)d_in[4];   // [T,N]
    float* out = (float*)d_out;
    float* ws  = (float*)d_ws;

    prep_kernel<<<1, 1024, 0, stream>>>(conn, ws);

    main_kernel<<<TN / 256, 256, 0, stream>>>(
        unit_outputs, target, input_spikes, out, ws);

    boost_kernel<<<(TN / 4) / 256, 256, 0, stream>>>(
        (const float4*)rand_bias, (float4*)out, ws);
}

// Round 4
// 204.648 us; speedup vs baseline: 1.0464x; 1.0464x over previous
//
#include <hip/hip_runtime.h>

// Problem constants (fixed by setup_inputs)
#define U     128
#define TN    (256 * 1024)        // T*N output elements
#define TN4   (TN / 4)            // float4 granularity (65536)
#define GJ    8                   // j-groups (j-split factor)
#define JPG   (U / GJ)            // 16 j per group
#define TILES 64                  // output tiles
#define TILE_F4 (TN4 / TILES)     // 1024 float4 = 16 KB per tile

// Native clang vector type — accepted by __builtin_nontemporal_load
typedef float vfloat4 __attribute__((ext_vector_type(4)));

// ws layout (floats):
//   [0] = sum(final), [1] = sum(input_spikes), [2..129] = w[j]
//   [256 ...) = partials: GJ buffers of TN floats each (8 MB total)

// Single block, 1024 threads: gated column sums of conn.
__global__ __launch_bounds__(1024) void prep_kernel(const float* __restrict__ conn,
                                                    float* __restrict__ ws) {
    __shared__ float part[8][U];
    int tid = threadIdx.x;
    int c = tid >> 7;          // 0..7  (i-chunk)
    int j = tid & 127;         // 0..127 (column)
    float s = 0.0f;
#pragma unroll
    for (int k = 0; k < 16; ++k) {
        float v = conn[(c * 16 + k) * U + j];
        s += (v > 0.1f) ? v : 0.0f;
    }
    part[c][j] = s;
    __syncthreads();
    if (tid < 2) ws[tid] = 0.0f;                 // zero accumulators (ws poisoned)
    if (tid < U) {
        float t = 0.0f;
#pragma unroll
        for (int cc = 0; cc < 8; ++cc) t += part[cc][tid];
        ws[2 + tid] = 3.0f * t;
    }
}

// Main: 512 blocks = 64 tiles x 8 j-groups. Each block reads 16 KB contiguous
// per j-step (4 vfloat4/thread), double-buffered, accumulates 16 j's into regs,
// writes one 16 KB partial tile.
__global__ __launch_bounds__(256) void main_kernel(const vfloat4* __restrict__ uo,
                                                   float* __restrict__ ws) {
    int tile = blockIdx.x & (TILES - 1);
    int g    = blockIdx.x / TILES;               // 0..GJ-1
    int tid  = threadIdx.x;

    const float* wp = ws + 2 + g * JPG;
    vfloat4* part = (vfloat4*)(ws + 256) + (size_t)g * TN4;

    size_t base = (size_t)tile * TILE_F4 + tid;  // thread's first float4 in tile
    const vfloat4* pu = uo + (size_t)(g * JPG) * TN4 + base;

    vfloat4 acc0 = 0.0f, acc1 = 0.0f, acc2 = 0.0f, acc3 = 0.0f;

    vfloat4 b0 = __builtin_nontemporal_load(pu + 0);
    vfloat4 b1 = __builtin_nontemporal_load(pu + 256);
    vfloat4 b2 = __builtin_nontemporal_load(pu + 512);
    vfloat4 b3 = __builtin_nontemporal_load(pu + 768);

    for (int jj = 0; jj < JPG; ++jj) {
        float wj = wp[jj];
        vfloat4 c0 = b0, c1 = b1, c2 = b2, c3 = b3;
        if (jj + 1 < JPG) {
            const vfloat4* pn = pu + (size_t)(jj + 1) * TN4;
            b0 = __builtin_nontemporal_load(pn + 0);
            b1 = __builtin_nontemporal_load(pn + 256);
            b2 = __builtin_nontemporal_load(pn + 512);
            b3 = __builtin_nontemporal_load(pn + 768);
        }
        acc0 += wj * c0;
        acc1 += wj * c1;
        acc2 += wj * c2;
        acc3 += wj * c3;
    }

    part[base + 0]   = acc0;   // normal stores: keep partials L2-resident
    part[base + 256] = acc1;
    part[base + 512] = acc2;
    part[base + 768] = acc3;
}

// Combine: sum the GJ partials, apply 0.5x + 1.5*target, write out,
// and reduce sum(final) and sum(input_spikes).
__global__ __launch_bounds__(256) void combine_kernel(const vfloat4* __restrict__ tgt,
                                                      const vfloat4* __restrict__ insp,
                                                      vfloat4* __restrict__ out,
                                                      float* __restrict__ ws) {
    int idx = blockIdx.x * 256 + threadIdx.x;    // 0..TN4-1
    const vfloat4* part = (const vfloat4*)(ws + 256);

    vfloat4 s = part[idx];
#pragma unroll
    for (int g = 1; g < GJ; ++g)
        s += part[(size_t)g * TN4 + idx];

    vfloat4 t = tgt[idx];
    vfloat4 r = s * 0.5f + 1.5f * t;
    out[idx] = r;

    vfloat4 is = insp[idx];
    float lsum = r.x + r.y + r.z + r.w;
    float lin  = is.x + is.y + is.z + is.w;
#pragma unroll
    for (int off = 32; off > 0; off >>= 1) {
        lsum += __shfl_down(lsum, off, 64);
        lin  += __shfl_down(lin,  off, 64);
    }
    __shared__ float red[8];
    int wave = threadIdx.x >> 6;
    int lane = threadIdx.x & 63;
    if (lane == 0) { red[wave] = lsum; red[4 + wave] = lin; }
    __syncthreads();
    if (threadIdx.x == 0) {
        atomicAdd(&ws[0], red[0] + red[1] + red[2] + red[3]);
        atomicAdd(&ws[1], red[4] + red[5] + red[6] + red[7]);
    }
}

// Conditional boost (branch dead for this data; kept generic).
__global__ __launch_bounds__(256) void boost_kernel(const vfloat4* __restrict__ rb,
                                                    vfloat4* __restrict__ out,
                                                    const float* __restrict__ ws) {
    float mean    = ws[0] * (1.0f / TN);
    float in_rate = ws[1] * (1000.0f / TN);
    float target_mean = (in_rate + 20.0f) * 0.01f;
    float boost = fmaxf(0.0f, target_mean - mean);
    if (mean < 0.2f) {
        int idx = blockIdx.x * 256 + threadIdx.x;
        vfloat4 o = out[idx];
        vfloat4 r = rb[idx];
        out[idx] = o + r * (boost * 2.0f);
    }
}

extern "C" void kernel_launch(void* const* d_in, const int* in_sizes, int n_in,
                              void* d_out, int out_size, void* d_ws, size_t ws_size,
                              hipStream_t stream) {
    const float* input_spikes = (const float*)d_in[0];   // [T,N]
    const float* unit_outputs = (const float*)d_in[1];   // [U,T,N]
    const float* conn         = (const float*)d_in[2];   // [U,U]
    const float* target       = (const float*)d_in[3];   // [T,N]
    const float* rand_bias    = (const float*)d_in[4];   // [T,N]
    float* out = (float*)d_out;
    float* ws  = (float*)d_ws;

    prep_kernel<<<1, 1024, 0, stream>>>(conn, ws);

    main_kernel<<<TILES * GJ, 256, 0, stream>>>(
        (const vfloat4*)unit_outputs, ws);

    combine_kernel<<<TN4 / 256, 256, 0, stream>>>(
        (const vfloat4*)target, (const vfloat4*)input_spikes, (vfloat4*)out, ws);

    boost_kernel<<<TN4 / 256, 256, 0, stream>>>(
        (const vfloat4*)rand_bias, (vfloat4*)out, ws);
}

// Round 5
// 192.799 us; speedup vs baseline: 1.1108x; 1.0615x over previous
//
#include <hip/hip_runtime.h>

// Problem constants (fixed by setup_inputs)
#define U    128
#define TN   (256 * 1024)         // T*N output elements
#define TN4  (TN / 4)             // float4 granularity (65536)
#define NBLK 256                  // blocks in fused kernel (= TN4 / 256)

// Native clang vector type — accepted by __builtin_nontemporal_load
typedef float vfloat4 __attribute__((ext_vector_type(4)));

// ws layout (floats):
//   [0..255]   per-block partial sum(final)
//   [256..511] per-block partial sum(input_spikes)
// Plain stores only — no zero-init needed on poisoned ws, no atomics.

// Fused: per-block w[] compute (redundant, L2-amortized) + weighted j-reduction
// + epilogue + per-block partial sums. One dispatch does all heavy traffic.
__global__ __launch_bounds__(256) void fused_kernel(const float*   __restrict__ conn,
                                                    const vfloat4* __restrict__ uo,
                                                    const vfloat4* __restrict__ tgt,
                                                    const vfloat4* __restrict__ insp,
                                                    vfloat4*       __restrict__ out,
                                                    float*         __restrict__ ws) {
    __shared__ float wpart[2][U];
    __shared__ float w_s[U];
    int tid = threadIdx.x;

    // --- w[j] = 3 * sum_i gated(conn[i][j]); 256 threads = 128 cols x 2 halves
    {
        int j = tid & 127;
        int h = tid >> 7;                        // 0/1: which half of i-range
        const float* cp = conn + (size_t)(h * 64) * U + j;
        float s = 0.0f;
#pragma unroll
        for (int k = 0; k < 64; ++k) {
            float v = cp[(size_t)k * U];         // consecutive j -> coalesced
            s += (v > 0.1f) ? v : 0.0f;
        }
        wpart[h][j] = s;
    }
    __syncthreads();
    if (tid < U) w_s[tid] = 3.0f * (wpart[0][tid] + wpart[1][tid]);
    __syncthreads();

    // --- weighted reduction over j: one float4 per thread, 16-deep ILP
    int idx = blockIdx.x * 256 + tid;            // 0..TN4-1
    const vfloat4* p = uo + idx;
    vfloat4 acc = 0.0f;
#pragma unroll 16
    for (int jj = 0; jj < U; ++jj)
        acc += w_s[jj] * __builtin_nontemporal_load(p + (size_t)jj * TN4);

    vfloat4 t = tgt[idx];
    vfloat4 r = acc * 0.5f + 1.5f * t;
    out[idx] = r;

    // --- block partial sums: sum(final), sum(input_spikes)
    vfloat4 is = insp[idx];
    float lsum = r.x + r.y + r.z + r.w;
    float lin  = is.x + is.y + is.z + is.w;
#pragma unroll
    for (int off = 32; off > 0; off >>= 1) {
        lsum += __shfl_down(lsum, off, 64);
        lin  += __shfl_down(lin,  off, 64);
    }
    __shared__ float red[8];
    int wave = tid >> 6;
    int lane = tid & 63;
    if (lane == 0) { red[wave] = lsum; red[4 + wave] = lin; }
    __syncthreads();
    if (tid == 0) {
        ws[blockIdx.x]        = red[0] + red[1] + red[2] + red[3];
        ws[NBLK + blockIdx.x] = red[4] + red[5] + red[6] + red[7];
    }
}

// Boost: every block tree-reduces the 256+256 partials (L2-hot) itself, then
// conditionally applies. Branch is dead for this data (mean >> 0.2).
__global__ __launch_bounds__(256) void boost_kernel(const vfloat4* __restrict__ rb,
                                                    vfloat4*       __restrict__ out,
                                                    const float*   __restrict__ ws) {
    int tid = threadIdx.x;
    float lsum = ws[tid];                        // 256 partials, one per thread
    float lin  = ws[NBLK + tid];
#pragma unroll
    for (int off = 32; off > 0; off >>= 1) {
        lsum += __shfl_down(lsum, off, 64);
        lin  += __shfl_down(lin,  off, 64);
    }
    __shared__ float red[8];
    int wave = tid >> 6;
    int lane = tid & 63;
    if (lane == 0) { red[wave] = lsum; red[4 + wave] = lin; }
    __syncthreads();
    float tot = red[0] + red[1] + red[2] + red[3];
    float tin = red[4] + red[5] + red[6] + red[7];

    float mean        = tot * (1.0f / TN);
    float in_rate     = tin * (1000.0f / TN);    // input_spikes.mean() * 1000
    float target_mean = (in_rate + 20.0f) * 0.01f;
    float boost       = fmaxf(0.0f, target_mean - mean);
    if (mean < 0.2f) {
        int idx = blockIdx.x * 256 + tid;
        out[idx] += rb[idx] * (boost * 2.0f);
    }
}

extern "C" void kernel_launch(void* const* d_in, const int* in_sizes, int n_in,
                              void* d_out, int out_size, void* d_ws, size_t ws_size,
                              hipStream_t stream) {
    const float* input_spikes = (const float*)d_in[0];   // [T,N]
    const float* unit_outputs = (const float*)d_in[1];   // [U,T,N]
    const float* conn         = (const float*)d_in[2];   // [U,U]
    const float* target       = (const float*)d_in[3];   // [T,N]
    const float* rand_bias    = (const float*)d_in[4];   // [T,N]
    float* out = (float*)d_out;
    float* ws  = (float*)d_ws;

    fused_kernel<<<NBLK, 256, 0, stream>>>(
        conn, (const vfloat4*)unit_outputs, (const vfloat4*)target,
        (const vfloat4*)input_spikes, (vfloat4*)out, ws);

    boost_kernel<<<TN4 / 256, 256, 0, stream>>>(
        (const vfloat4*)rand_bias, (vfloat4*)out, ws);
}